// Round 1
// 135.024 us; speedup vs baseline: 1.0138x; 1.0138x over previous
//
#include <hip/hip_runtime.h>
#include <math.h>

#define U_ 4096
#define T_ 200
#define K_ 64
#define Q_ 10000
#define H_ 128
#define UPB 8  // users per block in scan2 (wave = user)

__device__ __forceinline__ float gelu_f(float x) {
  // exact erf GELU (matches jax.nn.gelu approximate=False)
  return 0.5f * x * (1.0f + erff(x * 0.70710678118654752440f));
}

// ---------------------------------------------------------------------------
// K1 (R7 rewrite of layer-2 LDS access): MLP table over (q, resp) ->
// tab4[2q+rp] = (r, mu, ts, td), plus fused kc_of_q = argmax_k kmap[q][k].
//
// R6 profile model: layer-2 issued 6 ds_read_b32 per k-iter (2 strided W2s +
// 4 separate h1 broadcasts) vs 8 FMAs -> LDS-issue-bound (~35 cyc issue vs
// 16 cyc VALU per iter, m134 ds_read_b32 ~5.8 cyc). R7: lane owns output
// pair (2*lane, 2*lane+1) -> one ds_read_b64 of W2s (stride-2 floats = 4-way
// over 4-clk b64 = conflict-free); h1 transposed to h1t[hidden][pair]
// (stride 16, rows 16B-aligned) -> one uniform ds_read_b128 broadcast.
// 6 LDS instrs/iter -> 2. LDS total stays 40 KB -> 4 blocks/CU unchanged.
// FMA order per output unchanged -> bitwise-identical results.
// ---------------------------------------------------------------------------
__global__ __launch_bounds__(256, 4) void mlp_table_kernel(
    const float* __restrict__ diff_mu, const float* __restrict__ disc_mu,
    const float* __restrict__ W1, const float* __restrict__ b1,
    const float* __restrict__ W2, const float* __restrict__ b2,
    const float* __restrict__ W3, const float* __restrict__ b3,
    const unsigned char* __restrict__ kmap,
    float4* __restrict__ tab4, int* __restrict__ kc_of_q) {
  __shared__ __align__(16) float W2s[64 * H_];   // 32 KB: one half of W2 at a time
  __shared__ __align__(16) float h1t[H_][16];    // 8 KB: h1 transposed [hidden][pair]

  const int tid = threadIdx.x;
  const int base = blockIdx.x * 16;  // 1250*16 = 20000 exact

  // lower half of W2, vectorized: 2048 float4 / 256 threads = 8 iters
  {
    const float4* src = (const float4*)W2;
    float4* dst = (float4*)W2s;
    for (int v = tid; v < (64 * H_) / 4; v += 256) dst[v] = src[v];
  }

  if (blockIdx.x < 40) {
    int q = blockIdx.x * 256 + tid;
    if (q < Q_) {
      const unsigned char* km = kmap + (size_t)q * K_;
      int kc = 0;
#pragma unroll
      for (int k = 0; k < K_; ++k)
        if (km[k]) kc = k;  // one-hot -> single set index
      kc_of_q[q] = kc;
    }
  }

  // layer 1 -> transposed store. v-mapping pl=v&15, j=v>>4 gives stride-1
  // LDS writes across a wave (conflict-free).
  for (int v = tid; v < 16 * H_; v += 256) {
    int pl = v & 15, j = v >> 4;
    int pg = base + pl;
    int q = pg >> 1;
    float rf = (float)(pg & 1);
    float td = diff_mu[q], ts = disc_mu[q];
    float a = b1[j];
    a += td * W1[j];
    a += ts * W1[H_ + j];
    a += rf * W1[2 * H_ + j];
    h1t[j][pl] = gelu_f(a);
  }
  __syncthreads();

  // layer 2: wave w handles pairs 4w..4w+3; lane -> outputs 2*lane, 2*lane+1
  const int w = tid >> 6, lane = tid & 63;
  const int j0 = 2 * lane;
  float a0[4] = {0.f, 0.f, 0.f, 0.f}, a1[4] = {0.f, 0.f, 0.f, 0.f};

#pragma clang loop unroll_count(8)
  for (int k = 0; k < 64; ++k) {
    float2 w2 = *(const float2*)&W2s[k * H_ + j0];         // ds_read_b64
    float4 hq = *(const float4*)&h1t[k][4 * w];            // uniform ds_read_b128
    const float* hp = (const float*)&hq;
#pragma unroll
    for (int p = 0; p < 4; ++p) {
      a0[p] = fmaf(w2.x, hp[p], a0[p]);
      a1[p] = fmaf(w2.y, hp[p], a1[p]);
    }
  }
  __syncthreads();
  // upper half of W2
  {
    const float4* src = (const float4*)(W2 + 64 * H_);
    float4* dst = (float4*)W2s;
    for (int v = tid; v < (64 * H_) / 4; v += 256) dst[v] = src[v];
  }
  __syncthreads();
#pragma clang loop unroll_count(8)
  for (int k = 0; k < 64; ++k) {
    float2 w2 = *(const float2*)&W2s[k * H_ + j0];
    float4 hq = *(const float4*)&h1t[64 + k][4 * w];
    const float* hp = (const float*)&hq;
#pragma unroll
    for (int p = 0; p < 4; ++p) {
      a0[p] = fmaf(w2.x, hp[p], a0[p]);
      a1[p] = fmaf(w2.y, hp[p], a1[p]);
    }
  }

  // layer 3 + head math. lane holds outputs j0=2*lane, j0+1:
  // W3 rows for (j0, j0+1) are 4 consecutive floats -> one float4.
  float4 w3v = ((const float4*)W3)[lane];   // {W3[j0][0], W3[j0][1], W3[j0+1][0], W3[j0+1][1]}
  float2 b2v = *(const float2*)&b2[j0];
  float b30 = b3[0], b31 = b3[1];
#pragma unroll
  for (int p = 0; p < 4; ++p) {
    float h2a = gelu_f(a0[p] + b2v.x);
    float h2b = gelu_f(a1[p] + b2v.y);
    float s0 = h2a * w3v.x + h2b * w3v.z;
    float s1 = h2a * w3v.y + h2b * w3v.w;
#pragma unroll
    for (int off = 32; off > 0; off >>= 1) {
      s0 += __shfl_xor(s0, off, 64);
      s1 += __shfl_xor(s1, off, 64);
    }
    if (lane == 0) {
      float mu = gelu_f(s0 + b30);
      float lv = gelu_f(s1 + b31);
      float sd = fmaxf(expf(0.5f * lv), 1e-8f);
      int pg = base + w * 4 + p;
      int q = pg >> 1;
      tab4[pg] = make_float4(1.0f / (sd * sd), mu, disc_mu[q], diff_mu[q]);
    }
  }
}

// ---------------------------------------------------------------------------
// K2: wave = user, lane = KC forward scan. UNCHANGED from R6 (isolate the K1
// LDS rewrite this round).
// ---------------------------------------------------------------------------
__global__ __launch_bounds__(512) void scan2_kernel(
    const int* __restrict__ q_id, const int* __restrict__ resp,
    const float4* __restrict__ tab4, const int* __restrict__ kc_of_q,
    float* __restrict__ out) {
  __shared__ float2 bcs[T_ * (UPB + 1)];    // [t][u], u-stride 9: (r,mu)->(b,c); .x later = ability
  __shared__ unsigned char kcs[T_ * UPB];   // [t][u]

  const int tid = threadIdx.x;
  const int lane = tid & 63;
  const int ul = tid >> 6;                  // wave index = local user
  const int gu = blockIdx.x * UPB + ul;     // global user

  // ---- phase 0: each wave gathers its own user's 200 steps ----
  float tts[4], ttd[4];
  const int* qrow = q_id + (size_t)gu * T_;
  const int* rrow = resp + (size_t)gu * T_;
#pragma unroll
  for (int tile = 0; tile < 4; ++tile) {
    int t = tile * 64 + lane;
    if (t < T_) {
      int q = qrow[t];                      // coalesced
      int rp = rrow[t];                     // coalesced
      float4 f = tab4[q * 2 + rp];          // L2-resident 320 KB
      bcs[t * (UPB + 1) + ul] = make_float2(f.x, f.y);  // (r, mu)
      kcs[t * UPB + ul] = (unsigned char)kc_of_q[q];
      tts[tile] = f.z;                      // ts stays in registers
      ttd[tile] = f.w;                      // td stays in registers
    }
  }
  __syncthreads();

  // ---- phase 1: backward recursion, wave 0, lane = user (8 active) ----
  if (tid < 64) {
    const bool act = lane < UPB;
    const int ll = act ? lane : 0;
    float b = 1.0f, c = 0.0f;
#pragma unroll 8
    for (int t = T_ - 1; t >= 0; --t) {
      float2 rm_ = bcs[t * (UPB + 1) + ll];   // static offsets: prefetchable
      float x_ = 2.0f + rm_.x - b;            // 1 + r + (1 - b_next)
      float ib = __builtin_amdgcn_rcpf(x_);
      ib = ib * (2.0f - x_ * ib);             // Newton step (passing since R3)
      b = ib;
      c = b * fmaf(rm_.x, rm_.y, c);
      if (act) bcs[t * (UPB + 1) + lane] = make_float2(b, c);
    }
  }
  __syncthreads();

  // ---- phase 2: forward scan, per wave, lane = KC ----
  float x = 0.0f;  // ability state of KC == lane for this wave's user
#pragma unroll 8
  for (int t = 0; t < T_; ++t) {
    float2 bc_ = bcs[t * (UPB + 1) + ul];   // uniform -> LDS broadcast
    int kc = (int)kcs[t * UPB + ul];        // uniform
    float xn = fmaf(bc_.x, x, bc_.y);
    bool hit = (lane == kc);
    x = hit ? xn : x;
    if (hit) bcs[t * (UPB + 1) + ul].x = xn;  // ability stash (1-lane write)
  }
  __syncthreads();

  // ---- epilogue ----
  float* logits = out;
  float* last = out + (size_t)U_ * T_;
#pragma unroll
  for (int tile = 0; tile < 4; ++tile) {
    int t = tile * 64 + lane;
    if (t < T_) {
      float ab = bcs[t * (UPB + 1) + ul].x;
      logits[(size_t)gu * T_ + t] = tts[tile] * (ab - ttd[tile]);  // coalesced
    }
  }
  last[(size_t)gu * K_ + lane] = x;  // last_ability_kc straight from registers
}

// ---------------------------------------------------------------------------
extern "C" void kernel_launch(void* const* d_in, const int* in_sizes, int n_in,
                              void* d_out, int out_size, void* d_ws,
                              size_t ws_size, hipStream_t stream) {
  // setup_inputs order:
  // 0 mask 1 q_id(i32,U*T) 2 kmap(bool,Q*K) 3 resp(i32) 4 diff_mu 5 disc_mu
  // 6 W1 7 b1 8 W2 9 b2 10 W3 11 b3
  const int* q_id = (const int*)d_in[1];
  const unsigned char* kmap = (const unsigned char*)d_in[2];
  const int* resp = (const int*)d_in[3];
  const float* diff_mu = (const float*)d_in[4];
  const float* disc_mu = (const float*)d_in[5];
  const float* W1 = (const float*)d_in[6];
  const float* b1 = (const float*)d_in[7];
  const float* W2 = (const float*)d_in[8];
  const float* b2 = (const float*)d_in[9];
  const float* W3 = (const float*)d_in[10];
  const float* b3 = (const float*)d_in[11];
  float* out = (float*)d_out;
  char* ws = (char*)d_ws;

  auto align512 = [](size_t x) { return (x + 511) & ~(size_t)511; };
  size_t o = 0;
  float4* tab4 = (float4*)(ws + o);  o = align512(o + (size_t)2 * Q_ * 16);
  int* kc_of_q = (int*)(ws + o);     o = align512(o + (size_t)Q_ * 4);
  (void)ws_size; (void)in_sizes; (void)n_in; (void)out_size;

  mlp_table_kernel<<<1250, 256, 0, stream>>>(diff_mu, disc_mu, W1, b1, W2, b2,
                                             W3, b3, kmap, tab4, kc_of_q);
  scan2_kernel<<<U_ / UPB, 512, 0, stream>>>(q_id, resp, tab4, kc_of_q, out);
}